// Round 14
// baseline (170.484 us; speedup 1.0000x reference)
//
#include <hip/hip_runtime.h>

// QNet forward, MI355X — R14: SINGLE obs pass; others persisted as bf16 in LDS.
// B=65536 rows, obs=1129 (37 self + 39*28 others).
// 256 thr (4 waves), 64 rows/block, grid 1024, LDS 162816 B -> 1 block/CU.
//
// R13 post-mortem: dur ~= device bytes / 6.9 TB/s (residency-blind streaming).
// Biggest removable bytes: pass-2 obs re-read (287MB). R14: pass-1 A loads go
// global->VGPR (coalesced), convert once to bf16 hi/lo; hi of cols 37..1128 is
// written to a PERSISTENT per-wave LDS arena (16 rows x 2192B); pass 2 reads
// agent fragments from the arena (ds_read_b64 x2, byte 56n+16s, 8-aligned) —
// ZERO global re-read. W_oth units revert to unshifted K=28 (trailing zeros).
// Arena writes land at byte ≡ 6 mod 16 -> u16/b64/b32/u16 split (all aligned).
// Arena row tails (idx 1092..1095) zeroed once (NaN x 0 hazard).
// B: glds quad-buffer as R13 (hi-only); ordering B(c) before A(c) per iter =>
// compiler's auto-wait on A(c) regs also guarantees B(c) arrival (in-order
// vmcnt retirement); s_barrier per chunk publishes B cross-wave.
// Softmax in-register; weights via __shfl owner (lane&48)|((1+n)&15),
// class (1+n)>>4 (R12-proven fixed map).
//
// Fragment maps (gfx950 16x16x32 bf16): A/B: row|col = lane&15, k = 8*(lane>>4)+i
//   C/D: col = lane&15, row = 4*(lane>>4) + reg
// Precision: logits 2-term (A hi+lo x B-hi), self/head 3-term, others 2-term
// (A-hi x B hi+lo) — identical rounding to R13 (absmax 9.77e-4).
//
// d_ws: 120 units of 128 bf16x8 (64 hi + 64 lo), 2KB each.
//   W_al: c*3+t | W_self: 108+c*2+t | W_oth (K=28, rows 28..31 zero): 112+t
//   W_ao: 114+t | W_emb: 116+t | W_out: 118+t

typedef __bf16 bf16x8 __attribute__((ext_vector_type(8)));
typedef float  f32x4  __attribute__((ext_vector_type(4)));

constexpr int OBS = 1129;
constexpr int AR_STRIDE = 2192;              // arena row stride (548 dw ≡ 4 mod 32 -> ~2-way banks)
constexpr int AR_WAVE   = 16 * AR_STRIDE;    // 35072
constexpr int HT_OFF    = 4 * AR_WAVE;       // 140288
constexpr int HT_WAVE   = 2560;              // hiT 1280 + loT 1280 (stride 80B)
constexpr int BQ_OFF    = HT_OFF + 4 * HT_WAVE;  // 150528; +12288 => 162816 total

#define MFMA(a, b, c) __builtin_amdgcn_mfma_f32_16x16x32_bf16((a), (b), (c), 0, 0, 0)

__device__ __forceinline__ float4 ld4(const float* p) {
    float4 v;
    __builtin_memcpy(&v, p, 16);
    return v;
}

__device__ __forceinline__ void split8(const float* a, bf16x8& h, bf16x8& l) {
#pragma unroll
    for (int i = 0; i < 8; ++i) {
        __bf16 hb = (__bf16)a[i];
        h[i] = hb;
        l[i] = (__bf16)(a[i] - (float)hb);
    }
}

__device__ __forceinline__ f32x4 mm3(bf16x8 ah, bf16x8 al, bf16x8 bh, bf16x8 bl, f32x4 c) {
    c = MFMA(ah, bh, c);
    c = MFMA(ah, bl, c);
    c = MFMA(al, bh, c);
    return c;
}

__device__ __forceinline__ void glds16(const void* g, void* l) {
    __builtin_amdgcn_global_load_lds((const __attribute__((address_space(1))) void*)g,
                                     (__attribute__((address_space(3))) void*)l, 16, 0, 0);
}

// hi/lo split of 8 floats into packed dwords (H = hi bf16 x8, L = lo bf16 x8)
__device__ __forceinline__ void cvt8(const float* av, uint4& H, uint4& L) {
    uint32_t hw[4], lw[4];
#pragma unroll
    for (int i = 0; i < 4; ++i) {
        float a0 = av[2 * i], a1 = av[2 * i + 1];
        __bf16 h0 = (__bf16)a0, h1 = (__bf16)a1;
        float r0 = a0 - (float)h0, r1 = a1 - (float)h1;
        __bf16 l0 = (__bf16)r0, l1 = (__bf16)r1;
        uint16_t uh0, uh1, ul0, ul1;
        __builtin_memcpy(&uh0, &h0, 2);
        __builtin_memcpy(&uh1, &h1, 2);
        __builtin_memcpy(&ul0, &l0, 2);
        __builtin_memcpy(&ul1, &l1, 2);
        hw[i] = (uint32_t)uh0 | ((uint32_t)uh1 << 16);
        lw[i] = (uint32_t)ul0 | ((uint32_t)ul1 << 16);
    }
    H.x = hw[0]; H.y = hw[1]; H.z = hw[2]; H.w = hw[3];
    L.x = lw[0]; L.y = lw[1]; L.z = lw[2]; L.w = lw[3];
}

// write 8 bf16 (H) to arena at byte wbase (wbase ≡ 6 mod 16): u16,b64,b32,u16
__device__ __forceinline__ void arena_wr8(char* AWB, int wbase, uint4 H) {
    *(uint16_t*)(AWB + wbase) = (uint16_t)H.x;                         // h0
    uint32_t m01 = (H.x >> 16) | (H.y << 16);                          // h1,h2
    uint32_t m23 = (H.y >> 16) | (H.z << 16);                          // h3,h4
    *(uint64_t*)(AWB + wbase + 2) = (uint64_t)m01 | ((uint64_t)m23 << 32);
    *(uint32_t*)(AWB + wbase + 10) = (H.z >> 16) | (H.w << 16);        // h5,h6
    *(uint16_t*)(AWB + wbase + 14) = (uint16_t)(H.w >> 16);            // h7
}

// ---------------- prep: split weights into fragment order ----------------
__global__ void prep_weights(const float* __restrict__ W_al,
                             const float* __restrict__ W_self,
                             const float* __restrict__ W_oth,
                             const float* __restrict__ W_ao,
                             const float* __restrict__ W_emb,
                             const float* __restrict__ W_out,
                             bf16x8* __restrict__ ws)
{
    const int u = blockIdx.x;     // 120 units
    const int l = threadIdx.x;    // 64 lanes
    const int s = l >> 4, col = l & 15;
    const float* W; int K, N, ld, c, t;
    if (u < 108)      { c = u / 3;         t = u % 3;         W = W_al;   K = 1129; N = 40; ld = 40; }
    else if (u < 112) { c = (u - 108) / 2; t = (u - 108) & 1; W = W_self; K = 37;   N = 32; ld = 32; }
    else if (u < 114) { c = 0;             t = u - 112;       W = W_oth;  K = 28;   N = 32; ld = 32; }
    else if (u < 116) { c = 0;             t = u - 114;       W = W_ao;   K = 32;   N = 32; ld = 32; }
    else if (u < 118) { c = 0;             t = u - 116;       W = W_emb;  K = 32;   N = 32; ld = 32; }
    else              { c = 0;             t = u - 118;       W = W_out;  K = 32;   N = 21; ld = 21; }
    const int j = t * 16 + col;
    bf16x8 h, lo;
#pragma unroll
    for (int i = 0; i < 8; ++i) {
        int k = c * 32 + s * 8 + i;
        float w = (k < K && j < N) ? W[k * ld + j] : 0.f;
        __bf16 hb = (__bf16)w;
        h[i]  = hb;
        lo[i] = (__bf16)(w - (float)hb);
    }
    ws[u * 128 + l]      = h;
    ws[u * 128 + 64 + l] = lo;
}

// ---------------- main kernel: 256 threads (4 waves), 64 rows ----------------
__global__ __launch_bounds__(256, 1)
void qnet_fwd(const float* __restrict__ obs,
              const float* __restrict__ b_al,
              const float* __restrict__ b_ao,
              const float* __restrict__ b_emb,
              const float* __restrict__ b_out,
              const bf16x8* __restrict__ wf,
              float* __restrict__ out)
{
    __shared__ __align__(16) char arena[162816];

    const int t    = threadIdx.x;
    const int lane = t & 63;
    const int wv   = t >> 6;
    const int s    = lane >> 4;
    const int cq   = lane & 15;
    const int grp  = lane & 48;
    const int rowbase = blockIdx.x * 64 + wv * 16;
    const float* __restrict__ orow = obs + (size_t)(rowbase + cq) * OBS;
    const char* __restrict__ wfb = (const char*)wf;

    char* const AWB = arena + wv * AR_WAVE;             // persistent others-hi arena
    char* const HT  = arena + HT_OFF + wv * HT_WAVE;    // transient hi [16][stride 80]
    char* const LT_ = HT + 1280;                        // transient lo
    char* const BQ  = arena + BQ_OFF;                   // B quad (4 x 3072)
    const int bt = wv % 3;                              // B piece staged by this wave

    const f32x4 zf = {0.f, 0.f, 0.f, 0.f};

    // zero arena row tails (idx 1092..1095 -> bytes 2184..2191): NaN x 0 hazard
    if (lane < 16) *(uint64_t*)(AWB + lane * AR_STRIDE + 2184) = 0;

    // pass-1 A addressing: lane -> row lane>>2, col-group 8*(lane&3)
    const int arow  = lane >> 2;
    const int acol8 = lane & 3;
    const float* aptr = obs + (size_t)(rowbase + arow) * OBS + 8 * acol8;

#define STAGE_B(C)                                                             \
    glds16(wfb + (size_t)(C) * 6144 + (size_t)bt * 2048 + lane * 16,           \
           BQ + ((C) & 3) * 3072 + bt * 1024)

    // ================= pass 1: logits = obs @ W_al =================
    f32x4 acc0 = zf, acc1 = zf, acc2 = zf;
    float4 rA0, rA1, rB0, rB1, rC0, rC1;

#define P1IT(C, RA, RB, DOA, DOB)                                              \
    do {                                                                       \
        float av[8] = {(RA).x, (RA).y, (RA).z, (RA).w,                         \
                       (RB).x, (RB).y, (RB).z, (RB).w};                        \
        uint4 H, L;                                                            \
        cvt8(av, H, L);                                                        \
        *(uint4*)(HT  + arow * 80 + 16 * acol8) = H;                           \
        *(uint4*)(LT_ + arow * 80 + 16 * acol8) = L;                           \
        if ((C) >= 2) {                                                        \
            arena_wr8(AWB, arow * AR_STRIDE + 64 * (C) + 16 * acol8 - 74, H);  \
        } else if ((C) == 1) {                                                 \
            if (acol8 == 0) {       /* cols 32..39: valid 37,38,39 = h5,h6,h7 */\
                *(uint32_t*)(AWB + arow * AR_STRIDE) = (H.z >> 16) | (H.w << 16);\
                *(uint16_t*)(AWB + arow * AR_STRIDE + 4) = (uint16_t)(H.w >> 16);\
            } else {                                                           \
                arena_wr8(AWB, arow * AR_STRIDE + 16 * acol8 - 10, H);         \
            }                                                                  \
        }                                                                      \
        asm volatile("s_waitcnt lgkmcnt(0)" ::: "memory");                     \
        __builtin_amdgcn_s_barrier();                                          \
        __builtin_amdgcn_sched_barrier(0);                                     \
        const char* _bp = BQ + ((C) & 3) * 3072;                               \
        bf16x8 ah = *(const bf16x8*)(HT  + cq * 80 + 16 * s);                  \
        bf16x8 al = *(const bf16x8*)(LT_ + cq * 80 + 16 * s);                  \
        bf16x8 b0 = *(const bf16x8*)(_bp + lane * 16);                         \
        bf16x8 b1 = *(const bf16x8*)(_bp + 1024 + lane * 16);                  \
        bf16x8 b2 = *(const bf16x8*)(_bp + 2048 + lane * 16);                  \
        asm volatile("s_waitcnt lgkmcnt(0)" ::: "memory");                     \
        __builtin_amdgcn_sched_barrier(0);                                     \
        if (DOB) STAGE_B((C) + 3);                                             \
        __builtin_amdgcn_sched_barrier(0);                                     \
        if (DOA) {                                                             \
            (RA) = ld4(aptr + 32 * ((C) + 3));                                 \
            (RB) = ld4(aptr + 32 * ((C) + 3) + 4);                             \
        }                                                                      \
        __builtin_amdgcn_sched_barrier(0);                                     \
        acc0 = MFMA(ah, b0, acc0); acc0 = MFMA(al, b0, acc0);                  \
        acc1 = MFMA(ah, b1, acc1); acc1 = MFMA(al, b1, acc1);                  \
        acc2 = MFMA(ah, b2, acc2); acc2 = MFMA(al, b2, acc2);                  \
    } while (0)

    // prologue: B(c) issued BEFORE A(c) so A-reg wait implies B arrival
    STAGE_B(0); __builtin_amdgcn_sched_barrier(0);
    rA0 = ld4(aptr);        rA1 = ld4(aptr + 4);   __builtin_amdgcn_sched_barrier(0);
    STAGE_B(1); __builtin_amdgcn_sched_barrier(0);
    rB0 = ld4(aptr + 32);   rB1 = ld4(aptr + 36);  __builtin_amdgcn_sched_barrier(0);
    STAGE_B(2); __builtin_amdgcn_sched_barrier(0);
    rC0 = ld4(aptr + 64);   rC1 = ld4(aptr + 68);  __builtin_amdgcn_sched_barrier(0);

    for (int g = 0; g < 11; ++g) {
        const int c = 3 * g;
        P1IT(c,     rA0, rA1, (c + 3) <= 34, (c + 3) <= 35);
        P1IT(c + 1, rB0, rB1, (c + 4) <= 34, (c + 4) <= 35);
        P1IT(c + 2, rC0, rC1, (c + 5) <= 34, (c + 5) <= 35);
    }
    P1IT(33, rA0, rA1, false, false);
    P1IT(34, rB0, rB1, false, false);

    {   // peeled chunk 35 (cols 1120..1151; valid <= 1128), OOB-guarded loads
        float av[8] = {0, 0, 0, 0, 0, 0, 0, 0};
        if (acol8 == 0) {
            float4 p = ld4(aptr + 1120), q = ld4(aptr + 1124);
            av[0] = p.x; av[1] = p.y; av[2] = p.z; av[3] = p.w;
            av[4] = q.x; av[5] = q.y; av[6] = q.z; av[7] = q.w;
        } else if (acol8 == 1) {
            av[0] = *(aptr + 1120);            // row*OBS + 8 + 1120 = col 1128
        }
        uint4 H, L;
        cvt8(av, H, L);
        *(uint4*)(HT  + arow * 80 + 16 * acol8) = H;
        *(uint4*)(LT_ + arow * 80 + 16 * acol8) = L;
        if (acol8 == 0)      arena_wr8(AWB, arow * AR_STRIDE + 2166, H);   // cols 1120..1127
        else if (acol8 == 1) *(uint16_t*)(AWB + arow * AR_STRIDE + 2182) = (uint16_t)H.x; // col 1128
        asm volatile("s_waitcnt vmcnt(0)" ::: "memory");   // all waves' B(35) staged
        asm volatile("s_waitcnt lgkmcnt(0)" ::: "memory");
        __builtin_amdgcn_s_barrier();
        __builtin_amdgcn_sched_barrier(0);
        const char* _bp = BQ + 3 * 3072;                   // 35 & 3
        bf16x8 ah = *(const bf16x8*)(HT  + cq * 80 + 16 * s);
        bf16x8 al = *(const bf16x8*)(LT_ + cq * 80 + 16 * s);
        bf16x8 b0 = *(const bf16x8*)(_bp + lane * 16);
        bf16x8 b1 = *(const bf16x8*)(_bp + 1024 + lane * 16);
        bf16x8 b2 = *(const bf16x8*)(_bp + 2048 + lane * 16);
        asm volatile("s_waitcnt lgkmcnt(0)" ::: "memory");
        __builtin_amdgcn_sched_barrier(0);
        acc0 = MFMA(ah, b0, acc0); acc0 = MFMA(al, b0, acc0);
        acc1 = MFMA(ah, b1, acc1); acc1 = MFMA(al, b1, acc1);
        acc2 = MFMA(ah, b2, acc2); acc2 = MFMA(al, b2, acc2);
    }

    // ===== softmax in registers (att weights remain in acc0/1/2) =====
    {
        const float bal0 = b_al[cq];
        const float bal1 = b_al[16 + cq];
        const bool  v2m  = (cq < 8);
        const float bal2 = v2m ? b_al[32 + cq] : 0.f;
#pragma unroll
        for (int j = 0; j < 4; ++j) {
            float v0 = acc0[j] + bal0, v1 = acc1[j] + bal1, vv = acc2[j] + bal2;
            float m = fmaxf(fmaxf(v0, v1), v2m ? vv : -3.4e38f);
#pragma unroll
            for (int d = 1; d < 16; d <<= 1) m = fmaxf(m, __shfl_xor(m, d));
            float e0 = __expf(v0 - m), e1 = __expf(v1 - m);
            float e2 = v2m ? __expf(vv - m) : 0.f;
            float sm = e0 + e1 + e2;
#pragma unroll
            for (int d = 1; d < 16; d <<= 1) sm += __shfl_xor(sm, d);
            float inv = 1.f / sm;
            acc0[j] = e0 * inv;
            acc1[j] = e1 * inv;
            acc2[j] = v2m ? e2 * inv : 0.f;
        }
    }

    // ================= pass 2: encodings, weighted sum (LDS-only A) =================
    const bf16x8* bo = wf + (size_t)112 * 128;
    const bf16x8 Boh0 = bo[lane],       Bol0 = bo[64 + lane];
    const bf16x8 Boh1 = bo[128 + lane], Bol1 = bo[192 + lane];

    f32x4 at0 = zf, at1 = zf;
    {   // self encoding (no relu), 3-term, cols 0..36 from global (tiny)
        f32x4 e0 = zf, e1 = zf;
        {
            float4 p = ld4(orow + s * 8), q = ld4(orow + s * 8 + 4);
            float av[8] = {p.x, p.y, p.z, p.w, q.x, q.y, q.z, q.w};
            bf16x8 ah, al; split8(av, ah, al);
            const bf16x8* bu = wf + (size_t)108 * 128;
            e0 = mm3(ah, al, bu[lane],       bu[64 + lane],  e0);
            e1 = mm3(ah, al, bu[128 + lane], bu[192 + lane], e1);
        }
        {
            float av[8] = {0, 0, 0, 0, 0, 0, 0, 0};
            if (s == 0) {
                float4 p = ld4(orow + 32);
                av[0] = p.x; av[1] = p.y; av[2] = p.z; av[3] = p.w;
                av[4] = orow[36];
            }
            bf16x8 ah, al; split8(av, ah, al);
            const bf16x8* bu = wf + (size_t)110 * 128;
            e0 = mm3(ah, al, bu[lane],       bu[64 + lane],  e0);
            e1 = mm3(ah, al, bu[128 + lane], bu[192 + lane], e1);
        }
#pragma unroll
        for (int j = 0; j < 4; ++j) {
            float w0 = __shfl(acc0[j], grp);        // att col 0 = self
            at0[j] = w0 * e0[j];
            at1[j] = w0 * e1[j];
        }
    }

#define RD_AH(N, AH)                                                           \
    do {                                                                       \
        const char* _p = AWB + cq * AR_STRIDE + 56 * (N) + 16 * s;             \
        uint64_t _qq[2];                                                       \
        _qq[0] = *(const uint64_t*)_p;                                         \
        _qq[1] = *(const uint64_t*)(_p + 8);                                   \
        __builtin_memcpy(&(AH), _qq, 16);                                      \
    } while (0)

#define PROC_TAIL(N, E0, E1, WC)                                               \
    do {                                                                       \
        const int _src = grp | (((N) + 1) & 15);                               \
        _Pragma("unroll")                                                      \
        for (int _j = 0; _j < 4; ++_j) {                                       \
            float _w = __shfl((WC)[_j], _src);                                 \
            at0[_j] += _w * fmaxf((E0)[_j], 0.f);                              \
            at1[_j] += _w * fmaxf((E1)[_j], 0.f);                              \
        }                                                                      \
    } while (0)

#define PROC_PAIR(N1, N2, W1, W2)                                              \
    do {                                                                       \
        bf16x8 _a1, _a2;                                                       \
        RD_AH(N1, _a1);                                                        \
        RD_AH(N2, _a2);                                                        \
        f32x4 _e10 = MFMA(_a1, Boh0, zf); f32x4 _e20 = MFMA(_a2, Boh0, zf);    \
        _e10 = MFMA(_a1, Bol0, _e10);     _e20 = MFMA(_a2, Bol0, _e20);        \
        f32x4 _e11 = MFMA(_a1, Boh1, zf); f32x4 _e21 = MFMA(_a2, Boh1, zf);    \
        _e11 = MFMA(_a1, Bol1, _e11);     _e21 = MFMA(_a2, Bol1, _e21);        \
        PROC_TAIL(N1, _e10, _e11, W1);                                         \
        PROC_TAIL(N2, _e20, _e21, W2);                                         \
    } while (0)

#define PROC_ONE(N, WC)                                                        \
    do {                                                                       \
        bf16x8 _a1; RD_AH(N, _a1);                                             \
        f32x4 _e0 = MFMA(_a1, Boh0, zf); _e0 = MFMA(_a1, Bol0, _e0);           \
        f32x4 _e1 = MFMA(_a1, Boh1, zf); _e1 = MFMA(_a1, Bol1, _e1);           \
        PROC_TAIL(N, _e0, _e1, WC);                                            \
    } while (0)

    // classes by att col 1+n: n in [0,14] -> acc0, [15,30] -> acc1, [31,38] -> acc2
    for (int n = 0; n < 14; n += 2)  PROC_PAIR(n, n + 1, acc0, acc0);
    PROC_ONE(14, acc0);
    for (int n = 15; n < 31; n += 2) PROC_PAIR(n, n + 1, acc1, acc1);
    for (int n = 31; n < 39; n += 2) PROC_PAIR(n, n + 1, acc2, acc2);

    // ============ head: 3 dense layers, wave-private LDS (HT/LT reuse) ============
    __bf16* hiw = (__bf16*)HT;
    __bf16* low = (__bf16*)LT_;
    f32x4 x0 = at0, x1 = at1;
#pragma unroll
    for (int L = 0; L < 3; ++L) {
        const int unit = 114 + L * 2;
        const float* bias = (L == 0) ? b_ao : (L == 1) ? b_emb : b_out;
        const int N = (L == 2) ? 21 : 32;
#pragma unroll
        for (int j = 0; j < 4; ++j) {
            const int row = s * 4 + j;
            __bf16 h0 = (__bf16)x0[j];
            hiw[row * 40 + cq] = h0;
            low[row * 40 + cq] = (__bf16)(x0[j] - (float)h0);
            __bf16 h1 = (__bf16)x1[j];
            hiw[row * 40 + 16 + cq] = h1;
            low[row * 40 + 16 + cq] = (__bf16)(x1[j] - (float)h1);
        }
        bf16x8 ah = *(const bf16x8*)&hiw[cq * 40 + s * 8];
        bf16x8 al = *(const bf16x8*)&low[cq * 40 + s * 8];
        const bf16x8* bu = wf + (size_t)unit * 128;
        f32x4 y0 = mm3(ah, al, bu[lane],       bu[64 + lane],  zf);
        f32x4 y1 = mm3(ah, al, bu[128 + lane], bu[192 + lane], zf);
        const float bc0 = bias[cq];
        const float bc1 = (16 + cq < N) ? bias[16 + cq] : 0.f;
#pragma unroll
        for (int j = 0; j < 4; ++j) {
            y0[j] += bc0;
            y1[j] += bc1;
            if (L < 2) { y0[j] = fmaxf(y0[j], 0.f); y1[j] = fmaxf(y1[j], 0.f); }
        }
        x0 = y0; x1 = y1;
    }

#pragma unroll
    for (int j = 0; j < 4; ++j) {
        const int row = rowbase + s * 4 + j;
        out[(size_t)row * 21 + cq] = x0[j];
        if (cq < 5) out[(size_t)row * 21 + 16 + cq] = x1[j];
    }
}

extern "C" void kernel_launch(void* const* d_in, const int* in_sizes, int n_in,
                              void* d_out, int out_size, void* d_ws, size_t ws_size,
                              hipStream_t stream) {
    const float* obs    = (const float*)d_in[0];
    const float* W_al   = (const float*)d_in[1];
    const float* b_al   = (const float*)d_in[2];
    const float* W_self = (const float*)d_in[3];
    const float* W_oth  = (const float*)d_in[5];
    const float* W_ao   = (const float*)d_in[7];
    const float* b_ao   = (const float*)d_in[8];
    const float* W_emb  = (const float*)d_in[9];
    const float* b_emb  = (const float*)d_in[10];
    const float* W_out  = (const float*)d_in[11];
    const float* b_out  = (const float*)d_in[12];
    float* out = (float*)d_out;
    bf16x8* ws = (bf16x8*)d_ws;

    prep_weights<<<120, 64, 0, stream>>>(W_al, W_self, W_oth, W_ao, W_emb, W_out, ws);

    const int B = in_sizes[0] / OBS;        // 65536
    qnet_fwd<<<B / 64, 256, 0, stream>>>(obs, b_al, b_ao, b_emb, b_out,
                                         (const bf16x8*)ws, out);
}